// Round 8
// baseline (134.017 us; speedup 1.0000x reference)
//
#include <hip/hip_runtime.h>

// DeLaN sin-net fused kernel for MI355X (gfx950) — R7: occupancy attack.
// = R5's proven per-tile structure (no pipelining — R6 proved it neutral),
//   but 1 wave per block (NT=64): LDS 44 KB -> 11.1 KB/block, 12 -> 14
//   waves/CU, finer scheduling. __launch_bounds__(64,4) caps VGPR at 128
//   (dropping R6's 24-reg staging pays for it). Kernel is latency-bound at
//   ~28% issue utilization; more resident waves is the lever.

#define NT 64

typedef short bf16x8 __attribute__((ext_vector_type(8)));
typedef float f32x4  __attribute__((ext_vector_type(4)));

__device__ inline unsigned short f2b(float f) {
    union { float f; unsigned u; } v; v.f = f;
    return (unsigned short)((v.u + 0x7FFF + ((v.u >> 16) & 1)) >> 16);
}
__device__ inline unsigned pk2(float lo, float hi) {
    return (unsigned)f2b(lo) | ((unsigned)f2b(hi) << 16);
}

#define INV2PI 0.15915494309189535f

// pack offsets in shorts, relative to ((ushort*)ws + 32); first 16 floats = BOUT
constexpr int PW_LD = 0;      // [nc][n][k] 2*512 : W1ld rows h=nc*16+n, k<7 w, k=7 b
constexpr int PW_LO = 1024;
constexpr int PW_G  = 2048;
constexpr int PB_MZ = 3072;   // [kc][nc][n][k] 3*1024 : kc0 PT, kc1 QT, kc2 MQT|BM
constexpr int PB_CZ = 6144;   //                        kc0 AT, kc1 BT, kc2 CQT|BC
constexpr int PB_O  = 9216;   // [kc][n][k] 3*512 : kc0 m_w2, kc1 c_w2, kc2 g_w2
constexpr int NPACK = 10752;

__global__ void precompute_kernel(
    const float* __restrict__ ld_w1, const float* __restrict__ ld_b1,
    const float* __restrict__ ld_w2, const float* __restrict__ ld_b2,
    const float* __restrict__ lo_w1, const float* __restrict__ lo_b1,
    const float* __restrict__ lo_w2, const float* __restrict__ lo_b2,
    const float* __restrict__ g_w1,  const float* __restrict__ g_b1,
    const float* __restrict__ g_w2,  const float* __restrict__ g_b2,
    const float* __restrict__ m_w1,  const float* __restrict__ m_b1,
    const float* __restrict__ m_w2,  const float* __restrict__ m_b2,
    const float* __restrict__ c_w1,  const float* __restrict__ c_b1,
    const float* __restrict__ c_w2,  const float* __restrict__ c_b2,
    float* __restrict__ ws)
{
    int i = blockIdx.x * blockDim.x + threadIdx.x;
    if (i < 16) { ws[i] = (i < 7) ? (m_b2[i] + c_b2[i] + g_b2[i]) : 0.f; return; }
    int r = i - 16;
    if (r >= NPACK) return;
    unsigned short* wp = (unsigned short*)ws + 32;
    float val = 0.f;
    if (r < 3072) {                                   // PW tables (W1 | b1)
        int tb = r / 1024, rr = r % 1024;
        int nc = rr >> 9, n = (rr >> 5) & 15, k = rr & 31, h = nc * 16 + n;
        const float* W1 = (tb == 0) ? ld_w1 : (tb == 1) ? lo_w1 : g_w1;
        const float* B1 = (tb == 0) ? ld_b1 : (tb == 1) ? lo_b1 : g_b1;
        if (h < 30) { if (k < 7) val = W1[h*7 + k]; else if (k == 7) val = B1[h]; }
    } else if (r < 6144) {                            // PB_MZ
        int rr = r - 3072; int kc = rr >> 10; rr &= 1023;
        int nc = rr >> 9, n = (rr >> 5) & 15, k = rr & 31, j = nc * 16 + n;
        if (j < 30) {
            if (kc == 0) {
                if (k < 30) { float a = 0.f;
                    for (int o = 0; o < 7; ++o) a += m_w1[j*35 + o] * ld_w2[o*30 + k];
                    val = a; }
            } else if (kc == 1) {
                if (k < 30) { float a = 0.f;
                    for (int o = 0; o < 21; ++o) a += m_w1[j*35 + 7 + o] * lo_w2[o*30 + k];
                    val = a; }
            } else {
                if (k < 7) val = m_w1[j*35 + 28 + k];
                else if (k == 7) { float a = m_b1[j];
                    for (int o = 0; o < 7;  ++o) a += m_w1[j*35 + o]     * ld_b2[o];
                    for (int o = 0; o < 21; ++o) a += m_w1[j*35 + 7 + o] * lo_b2[o];
                    val = a; }
            }
        }
    } else if (r < 9216) {                            // PB_CZ
        int rr = r - 6144; int kc = rr >> 10; rr &= 1023;
        int nc = rr >> 9, n = (rr >> 5) & 15, k = rr & 31, j = nc * 16 + n;
        if (j < 30) {
            if (kc == 0) {
                if (k < 30) { float a = 0.f;                 // AT[h=k][j]
                    for (int o = 0; o < 7; ++o) { float t = 0.f;
                        for (int d = 0; d < 7; ++d) t += c_w1[j*203 + o*7 + d] * ld_w1[k*7 + d];
                        a += ld_w2[o*30 + k] * t; }
                    val = a; }
            } else if (kc == 1) {
                if (k < 30) { float a = 0.f;                 // BT[h=k][j]
                    for (int o = 0; o < 21; ++o) { float t = 0.f;
                        for (int d = 0; d < 7; ++d) t += c_w1[j*203 + (7+o)*7 + d] * lo_w1[k*7 + d];
                        a += lo_w2[o*30 + k] * t; }
                    val = a; }
            } else {
                if (k < 7) val = c_w1[j*203 + 196 + k];
                else if (k == 7) val = c_b1[j];
            }
        }
    } else {                                          // PB_O
        int rr = r - 9216; int kc = rr >> 9, n = (rr >> 5) & 15, k = rr & 31;
        if (n < 7 && k < 30)
            val = ((kc == 0) ? m_w2 : (kc == 1) ? c_w2 : g_w2)[n*30 + k];
    }
    wp[r] = f2b(val);
}

#define MFMA(a, b, c) __builtin_amdgcn_mfma_f32_16x16x32_bf16((a), (b), (c), 0, 0, 0)

__global__ __launch_bounds__(NT, 4) void delan_main(
    const float* __restrict__ x, const float* __restrict__ ws, float* __restrict__ out)
{
    // DEDICATED regions, no overlap. One wave per block.
    __shared__ __align__(16) unsigned short xs2[NT * 24 + 32];   // 3136 B
    __shared__ __align__(16) unsigned short Lbuf[3968];          // 7936 B

    const int lane = threadIdx.x;            // == tid, one wave
    const int n15 = lane & 15, quad = lane >> 4;

    // ---- per-thread bf16 pack of one element: [q|1][qd|1][qdd|1], 24 shorts ----
    {
        const float* xp = x + (size_t)(blockIdx.x * NT + lane) * 21;
        float v[21];
#pragma unroll
        for (int d = 0; d < 21; ++d) v[d] = xp[d];
        int4* dst = (int4*)(xs2 + lane * 24);
#pragma unroll
        for (int g = 0; g < 3; ++g) {
            int4 u;
            u.x = (int)pk2(v[g*7 + 0], v[g*7 + 1]);
            u.y = (int)pk2(v[g*7 + 2], v[g*7 + 3]);
            u.z = (int)pk2(v[g*7 + 4], v[g*7 + 5]);
            u.w = (int)pk2(v[g*7 + 6], 1.0f);
            dst[g] = u;
        }
    }
    if (lane < 16) ((unsigned*)(xs2 + NT * 24))[lane] = 0;   // zero 64B tail pad
    __syncthreads();

    // transpose buffers (sin | cos | sig+sin_g)
    unsigned short* Ls = Lbuf;                  // [16][72]  sin_ld | sin_lo
    unsigned short* Lc = Ls + 1152;             // [16][72]  cos_ld | cos_lo
    unsigned short* Lg = Ls + 2304;             // [16][104] sig_m | sig_c | sin_g

    const unsigned short* wp = (const unsigned short*)ws + 32;
    const int fo = n15 * 32 + quad * 8;

    // ---- loop-invariant B-fragments (registers) ----
    bf16x8 bw_ld[2], bw_lo[2], bw_g[2], bm[3][2], bc[3][2], bo[3];
#pragma unroll
    for (int c = 0; c < 2; ++c) {
        bw_ld[c] = *(const bf16x8*)(wp + PW_LD + c*512 + fo);
        bw_lo[c] = *(const bf16x8*)(wp + PW_LO + c*512 + fo);
        bw_g[c]  = *(const bf16x8*)(wp + PW_G  + c*512 + fo);
#pragma unroll
        for (int kc = 0; kc < 3; ++kc) {
            bm[kc][c] = *(const bf16x8*)(wp + PB_MZ + kc*1024 + c*512 + fo);
            bc[kc][c] = *(const bf16x8*)(wp + PB_CZ + kc*1024 + c*512 + fo);
        }
    }
#pragma unroll
    for (int kc = 0; kc < 3; ++kc)
        bo[kc] = *(const bf16x8*)(wp + PB_O + kc*512 + fo);
    const float bout = ws[n15];        // 0 for n15 >= 7

    const f32x4 zero4 = {0.f, 0.f, 0.f, 0.f};

#pragma unroll 1
    for (int t = 0; t < 4; ++t) {
        const int elb = t * 16;                           // element base in block
        const unsigned short* ep = xs2 + (elb + n15) * 24;

        // ---- A-fragment + MFMA0 ----
        bf16x8 a0 = *(const bf16x8*)(ep + quad * 8);           // [q|1]
        f32x4 pld[2], plo[2], pg[2];
#pragma unroll
        for (int c = 0; c < 2; ++c) {
            pld[c] = MFMA(a0, bw_ld[c], zero4);
            plo[c] = MFMA(a0, bw_lo[c], zero4);
            pg[c]  = MFMA(a0, bw_g[c],  zero4);
        }

        // ---- sincos burst -> LDS transpose ----
#pragma unroll
        for (int c = 0; c < 2; ++c) {
            const int h = c * 16 + n15;
#pragma unroll
            for (int rg = 0; rg < 4; ++rg) {
                const int m = quad * 4 + rg;
                float r1 = pld[c][rg] * INV2PI;
                Ls[m*72 + h]       = f2b(__builtin_amdgcn_sinf(r1));
                Lc[m*72 + h]       = f2b(__builtin_amdgcn_cosf(r1));
                float r2 = plo[c][rg] * INV2PI;
                Ls[m*72 + 32 + h]  = f2b(__builtin_amdgcn_sinf(r2));
                Lc[m*72 + 32 + h]  = f2b(__builtin_amdgcn_cosf(r2));
                Lg[m*104 + 64 + h] = f2b(__builtin_amdgcn_sinf(pg[c][rg] * INV2PI));
            }
        }

        // ---- GEMM1: mz, cz ----
        bf16x8 as0 = *(const bf16x8*)(Ls + n15*72 + quad*8);
        bf16x8 as1 = *(const bf16x8*)(Ls + n15*72 + 32 + quad*8);
        bf16x8 ac0 = *(const bf16x8*)(Lc + n15*72 + quad*8);
        bf16x8 ac1 = *(const bf16x8*)(Lc + n15*72 + 32 + quad*8);
        bf16x8 aqd = *(const bf16x8*)(ep + 8 + quad * 8);      // [qDot|1]
        bf16x8 add = *(const bf16x8*)(ep + 16 + quad * 8);     // [qDDot|1]

        f32x4 mz[2], cz[2];
#pragma unroll
        for (int c = 0; c < 2; ++c) {
            f32x4 m_ = MFMA(as0, bm[0][c], zero4);
            m_ = MFMA(as1, bm[1][c], m_);
            mz[c] = MFMA(add, bm[2][c], m_);
            f32x4 c_ = MFMA(ac0, bc[0][c], zero4);
            c_ = MFMA(ac1, bc[1][c], c_);
            cz[c] = MFMA(aqd, bc[2][c], c_);
        }

        // ---- sigmoid -> Lg ----
#pragma unroll
        for (int c = 0; c < 2; ++c) {
            const int j = c * 16 + n15;
#pragma unroll
            for (int rg = 0; rg < 4; ++rg) {
                const int m = quad * 4 + rg;
                Lg[m*104 + j]      = f2b(__builtin_amdgcn_rcpf(1.f + __expf(-mz[c][rg])));
                Lg[m*104 + 32 + j] = f2b(__builtin_amdgcn_rcpf(1.f + __expf(-cz[c][rg])));
            }
        }

        // ---- GEMM2 + store ----
        bf16x8 ag0 = *(const bf16x8*)(Lg + n15*104 + quad*8);
        bf16x8 ag1 = *(const bf16x8*)(Lg + n15*104 + 32 + quad*8);
        bf16x8 ag2 = *(const bf16x8*)(Lg + n15*104 + 64 + quad*8);
        f32x4 o = MFMA(ag0, bo[0], zero4);
        o = MFMA(ag1, bo[1], o);
        o = MFMA(ag2, bo[2], o);

        if (n15 < 7) {
            const int eb = blockIdx.x * NT + elb;
            float* op = out + (size_t)(eb + quad * 4) * 7 + n15;
            op[0]  = o[0] + bout;
            op[7]  = o[1] + bout;
            op[14] = o[2] + bout;
            op[21] = o[3] + bout;
        }
    }
}

extern "C" void kernel_launch(void* const* d_in, const int* in_sizes, int n_in,
                              void* d_out, int out_size, void* d_ws, size_t ws_size,
                              hipStream_t stream)
{
    const float* x = (const float*)d_in[0];
    float* ws = (float*)d_ws;

    precompute_kernel<<<(16 + NPACK + 255) / 256, 256, 0, stream>>>(
        (const float*)d_in[1],  (const float*)d_in[2],
        (const float*)d_in[3],  (const float*)d_in[4],
        (const float*)d_in[5],  (const float*)d_in[6],
        (const float*)d_in[7],  (const float*)d_in[8],
        (const float*)d_in[9],  (const float*)d_in[10],
        (const float*)d_in[11], (const float*)d_in[12],
        (const float*)d_in[13], (const float*)d_in[14],
        (const float*)d_in[15], (const float*)d_in[16],
        (const float*)d_in[17], (const float*)d_in[18],
        (const float*)d_in[19], (const float*)d_in[20],
        ws);

    const int batch = out_size / 7;            // 262144
    const int nblk  = batch / NT;              // 4096
    delan_main<<<nblk, NT, 0, stream>>>(x, ws, (float*)d_out);
}

// Round 9
// 133.075 us; speedup vs baseline: 1.0071x; 1.0071x over previous
//
#include <hip/hip_runtime.h>

// DeLaN sin-net fused kernel for MI355X (gfx950) — R8: LDS-pipe attack.
// = R5's proven structure (NT=256, no pipelining), but LDS value pairs are
//   interleaved so every transpose write is ds_write_b32 instead of 2x b16:
//     Lsi[m][2h / 2h+1]  = sin_ld[h] / sin_lo[h]   (B rows PT/QT interleaved)
//     Lci[m][2h / 2h+1]  = cos_ld[h] / cos_lo[h]   (B rows AT/BT interleaved)
//     Lg [m][2j / 2j+1]  = sig_m[j]  / sig_c[j]    (B rows m_w2/c_w2 interleaved)
//   DS writes per tile 56 -> 32; reads & MFMA count unchanged (B layout moved
//   in precompute to match). Pads (k=60..63, 94..95) zeroed once per wave.

#define NT 256

typedef short bf16x8 __attribute__((ext_vector_type(8)));
typedef float f32x4  __attribute__((ext_vector_type(4)));

__device__ inline unsigned short f2b(float f) {
    union { float f; unsigned u; } v; v.f = f;
    return (unsigned short)((v.u + 0x7FFF + ((v.u >> 16) & 1)) >> 16);
}
__device__ inline unsigned pk2(float lo, float hi) {
    return (unsigned)f2b(lo) | ((unsigned)f2b(hi) << 16);
}

#define INV2PI 0.15915494309189535f

// pack offsets in shorts, relative to ((ushort*)ws + 32); first 16 floats = BOUT
constexpr int PW_LD = 0;      // [nc][n][k] 2*512 : W1ld rows h=nc*16+n, k<7 w, k=7 b
constexpr int PW_LO = 1024;
constexpr int PW_G  = 2048;
constexpr int PB_MZ = 3072;   // [kc][nc][n][k] : kc0/1 ki=kc*32+k: even PT[ki/2], odd QT[ki/2]; kc2 MQT|BM
constexpr int PB_CZ = 6144;   //                  kc0/1: even AT[ki/2], odd BT[ki/2];            kc2 CQT|BC
constexpr int PB_O  = 9216;   // [kc][n][k] : kc0/1 ki: even m_w2[ki/2], odd c_w2[ki/2]; kc2 g_w2
constexpr int NPACK = 10752;

__global__ void precompute_kernel(
    const float* __restrict__ ld_w1, const float* __restrict__ ld_b1,
    const float* __restrict__ ld_w2, const float* __restrict__ ld_b2,
    const float* __restrict__ lo_w1, const float* __restrict__ lo_b1,
    const float* __restrict__ lo_w2, const float* __restrict__ lo_b2,
    const float* __restrict__ g_w1,  const float* __restrict__ g_b1,
    const float* __restrict__ g_w2,  const float* __restrict__ g_b2,
    const float* __restrict__ m_w1,  const float* __restrict__ m_b1,
    const float* __restrict__ m_w2,  const float* __restrict__ m_b2,
    const float* __restrict__ c_w1,  const float* __restrict__ c_b1,
    const float* __restrict__ c_w2,  const float* __restrict__ c_b2,
    float* __restrict__ ws)
{
    int i = blockIdx.x * blockDim.x + threadIdx.x;
    if (i < 16) { ws[i] = (i < 7) ? (m_b2[i] + c_b2[i] + g_b2[i]) : 0.f; return; }
    int r = i - 16;
    if (r >= NPACK) return;
    unsigned short* wp = (unsigned short*)ws + 32;
    float val = 0.f;
    if (r < 3072) {                                   // PW tables (W1 | b1)
        int tb = r / 1024, rr = r % 1024;
        int nc = rr >> 9, n = (rr >> 5) & 15, k = rr & 31, h = nc * 16 + n;
        const float* W1 = (tb == 0) ? ld_w1 : (tb == 1) ? lo_w1 : g_w1;
        const float* B1 = (tb == 0) ? ld_b1 : (tb == 1) ? lo_b1 : g_b1;
        if (h < 30) { if (k < 7) val = W1[h*7 + k]; else if (k == 7) val = B1[h]; }
    } else if (r < 6144) {                            // PB_MZ
        int rr = r - 3072; int kc = rr >> 10; rr &= 1023;
        int nc = rr >> 9, n = (rr >> 5) & 15, k = rr & 31, j = nc * 16 + n;
        if (j < 30) {
            if (kc < 2) {
                int ki = kc * 32 + k;
                if (ki < 60) {
                    int h = ki >> 1;
                    if ((ki & 1) == 0) {              // PT[h][j]
                        float a = 0.f;
                        for (int o = 0; o < 7; ++o) a += m_w1[j*35 + o] * ld_w2[o*30 + h];
                        val = a;
                    } else {                          // QT[h][j]
                        float a = 0.f;
                        for (int o = 0; o < 21; ++o) a += m_w1[j*35 + 7 + o] * lo_w2[o*30 + h];
                        val = a;
                    }
                }
            } else {
                if (k < 7) val = m_w1[j*35 + 28 + k];
                else if (k == 7) { float a = m_b1[j];
                    for (int o = 0; o < 7;  ++o) a += m_w1[j*35 + o]     * ld_b2[o];
                    for (int o = 0; o < 21; ++o) a += m_w1[j*35 + 7 + o] * lo_b2[o];
                    val = a; }
            }
        }
    } else if (r < 9216) {                            // PB_CZ
        int rr = r - 6144; int kc = rr >> 10; rr &= 1023;
        int nc = rr >> 9, n = (rr >> 5) & 15, k = rr & 31, j = nc * 16 + n;
        if (j < 30) {
            if (kc < 2) {
                int ki = kc * 32 + k;
                if (ki < 60) {
                    int h = ki >> 1;
                    if ((ki & 1) == 0) {              // AT[h][j]
                        float a = 0.f;
                        for (int o = 0; o < 7; ++o) { float t = 0.f;
                            for (int d = 0; d < 7; ++d) t += c_w1[j*203 + o*7 + d] * ld_w1[h*7 + d];
                            a += ld_w2[o*30 + h] * t; }
                        val = a;
                    } else {                          // BT[h][j]
                        float a = 0.f;
                        for (int o = 0; o < 21; ++o) { float t = 0.f;
                            for (int d = 0; d < 7; ++d) t += c_w1[j*203 + (7+o)*7 + d] * lo_w1[h*7 + d];
                            a += lo_w2[o*30 + h] * t; }
                        val = a;
                    }
                }
            } else {
                if (k < 7) val = c_w1[j*203 + 196 + k];
                else if (k == 7) val = c_b1[j];
            }
        }
    } else {                                          // PB_O
        int rr = r - 9216; int kc = rr >> 9, n = (rr >> 5) & 15, k = rr & 31;
        if (n < 7) {
            if (kc < 2) {
                int ki = kc * 32 + k;
                if (ki < 60) {
                    int jj = ki >> 1;
                    val = (ki & 1) ? c_w2[n*30 + jj] : m_w2[n*30 + jj];
                }
            } else {
                if (k < 30) val = g_w2[n*30 + k];
            }
        }
    }
    wp[r] = f2b(val);
}

#define MFMA(a, b, c) __builtin_amdgcn_mfma_f32_16x16x32_bf16((a), (b), (c), 0, 0, 0)

__global__ __launch_bounds__(NT, 3) void delan_main(
    const float* __restrict__ x, const float* __restrict__ ws, float* __restrict__ out)
{
    // DEDICATED regions, no overlap:
    __shared__ __align__(16) unsigned short xs2[NT * 24 + 32];   // 12352 B
    __shared__ __align__(16) unsigned short Lbuf[4 * 3968];      // 31744 B

    const int tid = threadIdx.x;
    const int lane = tid & 63, wid = tid >> 6;
    const int n15 = lane & 15, quad = lane >> 4;

    // ---- per-thread bf16 pack of one element: [q|1][qd|1][qdd|1], 24 shorts ----
    {
        const float* xp = x + (size_t)(blockIdx.x * NT + tid) * 21;
        float v[21];
#pragma unroll
        for (int d = 0; d < 21; ++d) v[d] = xp[d];
        int4* dst = (int4*)(xs2 + tid * 24);
#pragma unroll
        for (int g = 0; g < 3; ++g) {
            int4 u;
            u.x = (int)pk2(v[g*7 + 0], v[g*7 + 1]);
            u.y = (int)pk2(v[g*7 + 2], v[g*7 + 3]);
            u.z = (int)pk2(v[g*7 + 4], v[g*7 + 5]);
            u.w = (int)pk2(v[g*7 + 6], 1.0f);
            dst[g] = u;
        }
    }
    if (tid < 16) ((unsigned*)(xs2 + NT * 24))[tid] = 0;   // zero 64B tail pad
    __syncthreads();

    // per-wave transpose buffers (interleaved layouts)
    unsigned short* Lsi = Lbuf + wid * 3968;    // [16][72] k=2h:sin_ld, 2h+1:sin_lo
    unsigned short* Lci = Lsi + 1152;           // [16][72] k=2h:cos_ld, 2h+1:cos_lo
    unsigned short* Lg  = Lsi + 2304;           // [16][104] 2j:sig_m,2j+1:sig_c | 64+h:sin_g

    // zero never-written pad cols once per wave (intra-wave, in-order DS)
    if (lane < 16) {
        const int m = lane;
        *(unsigned long long*)(Lsi + m*72  + 60) = 0ull;
        *(unsigned long long*)(Lci + m*72  + 60) = 0ull;
        *(unsigned long long*)(Lg  + m*104 + 60) = 0ull;
        *(unsigned*)(Lg + m*104 + 94) = 0u;
    }

    const unsigned short* wp = (const unsigned short*)ws + 32;
    const int fo = n15 * 32 + quad * 8;

    // ---- loop-invariant B-fragments (registers) ----
    bf16x8 bw_ld[2], bw_lo[2], bw_g[2], bm[3][2], bc[3][2], bo[3];
#pragma unroll
    for (int c = 0; c < 2; ++c) {
        bw_ld[c] = *(const bf16x8*)(wp + PW_LD + c*512 + fo);
        bw_lo[c] = *(const bf16x8*)(wp + PW_LO + c*512 + fo);
        bw_g[c]  = *(const bf16x8*)(wp + PW_G  + c*512 + fo);
#pragma unroll
        for (int kc = 0; kc < 3; ++kc) {
            bm[kc][c] = *(const bf16x8*)(wp + PB_MZ + kc*1024 + c*512 + fo);
            bc[kc][c] = *(const bf16x8*)(wp + PB_CZ + kc*1024 + c*512 + fo);
        }
    }
#pragma unroll
    for (int kc = 0; kc < 3; ++kc)
        bo[kc] = *(const bf16x8*)(wp + PB_O + kc*512 + fo);
    const float bout = ws[n15];        // 0 for n15 >= 7

    const f32x4 zero4 = {0.f, 0.f, 0.f, 0.f};

#pragma unroll 1
    for (int t = 0; t < 4; ++t) {
        const int elb = wid * 64 + t * 16;                // element base in block
        const unsigned short* ep = xs2 + (elb + n15) * 24;

        // ---- A-fragment + MFMA0 ----
        bf16x8 a0 = *(const bf16x8*)(ep + quad * 8);           // [q|1]
        f32x4 pld[2], plo[2], pg[2];
#pragma unroll
        for (int c = 0; c < 2; ++c) {
            pld[c] = MFMA(a0, bw_ld[c], zero4);
            plo[c] = MFMA(a0, bw_lo[c], zero4);
            pg[c]  = MFMA(a0, bw_g[c],  zero4);
        }

        // ---- sincos burst -> interleaved LDS transpose (b32 pair writes) ----
#pragma unroll
        for (int c = 0; c < 2; ++c) {
            const int h = c * 16 + n15;
#pragma unroll
            for (int rg = 0; rg < 4; ++rg) {
                const int m = quad * 4 + rg;
                float r1 = pld[c][rg] * INV2PI;
                float r2 = plo[c][rg] * INV2PI;
                float s1 = __builtin_amdgcn_sinf(r1), c1 = __builtin_amdgcn_cosf(r1);
                float s2 = __builtin_amdgcn_sinf(r2), c2 = __builtin_amdgcn_cosf(r2);
                *(unsigned*)(Lsi + m*72 + 2*h) = pk2(s1, s2);
                *(unsigned*)(Lci + m*72 + 2*h) = pk2(c1, c2);
                Lg[m*104 + 64 + h] = f2b(__builtin_amdgcn_sinf(pg[c][rg] * INV2PI));
            }
        }

        // ---- GEMM1: mz, cz (frags read the interleaved k-dim directly) ----
        bf16x8 as0 = *(const bf16x8*)(Lsi + n15*72 + quad*8);
        bf16x8 as1 = *(const bf16x8*)(Lsi + n15*72 + 32 + quad*8);
        bf16x8 ac0 = *(const bf16x8*)(Lci + n15*72 + quad*8);
        bf16x8 ac1 = *(const bf16x8*)(Lci + n15*72 + 32 + quad*8);
        bf16x8 aqd = *(const bf16x8*)(ep + 8 + quad * 8);      // [qDot|1]
        bf16x8 add = *(const bf16x8*)(ep + 16 + quad * 8);     // [qDDot|1]

        f32x4 mz[2], cz[2];
#pragma unroll
        for (int c = 0; c < 2; ++c) {
            f32x4 m_ = MFMA(as0, bm[0][c], zero4);
            m_ = MFMA(as1, bm[1][c], m_);
            mz[c] = MFMA(add, bm[2][c], m_);
            f32x4 c_ = MFMA(ac0, bc[0][c], zero4);
            c_ = MFMA(ac1, bc[1][c], c_);
            cz[c] = MFMA(aqd, bc[2][c], c_);
        }

        // ---- sigmoid -> Lg (b32 pair writes) ----
#pragma unroll
        for (int c = 0; c < 2; ++c) {
            const int j = c * 16 + n15;
#pragma unroll
            for (int rg = 0; rg < 4; ++rg) {
                const int m = quad * 4 + rg;
                float sm = __builtin_amdgcn_rcpf(1.f + __expf(-mz[c][rg]));
                float sc = __builtin_amdgcn_rcpf(1.f + __expf(-cz[c][rg]));
                *(unsigned*)(Lg + m*104 + 2*j) = pk2(sm, sc);
            }
        }

        // ---- GEMM2 + store ----
        bf16x8 ag0 = *(const bf16x8*)(Lg + n15*104 + quad*8);
        bf16x8 ag1 = *(const bf16x8*)(Lg + n15*104 + 32 + quad*8);
        bf16x8 ag2 = *(const bf16x8*)(Lg + n15*104 + 64 + quad*8);
        f32x4 o = MFMA(ag0, bo[0], zero4);
        o = MFMA(ag1, bo[1], o);
        o = MFMA(ag2, bo[2], o);

        if (n15 < 7) {
            const int eb = blockIdx.x * NT + elb;
            float* op = out + (size_t)(eb + quad * 4) * 7 + n15;
            op[0]  = o[0] + bout;
            op[7]  = o[1] + bout;
            op[14] = o[2] + bout;
            op[21] = o[3] + bout;
        }
    }
}

extern "C" void kernel_launch(void* const* d_in, const int* in_sizes, int n_in,
                              void* d_out, int out_size, void* d_ws, size_t ws_size,
                              hipStream_t stream)
{
    const float* x = (const float*)d_in[0];
    float* ws = (float*)d_ws;

    precompute_kernel<<<(16 + NPACK + 255) / 256, 256, 0, stream>>>(
        (const float*)d_in[1],  (const float*)d_in[2],
        (const float*)d_in[3],  (const float*)d_in[4],
        (const float*)d_in[5],  (const float*)d_in[6],
        (const float*)d_in[7],  (const float*)d_in[8],
        (const float*)d_in[9],  (const float*)d_in[10],
        (const float*)d_in[11], (const float*)d_in[12],
        (const float*)d_in[13], (const float*)d_in[14],
        (const float*)d_in[15], (const float*)d_in[16],
        (const float*)d_in[17], (const float*)d_in[18],
        (const float*)d_in[19], (const float*)d_in[20],
        ws);

    const int batch = out_size / 7;            // 262144
    const int nblk  = batch / NT;              // 1024
    delan_main<<<nblk, NT, 0, stream>>>(x, ws, (float*)d_out);
}